// Round 3
// baseline (114.632 us; speedup 1.0000x reference)
//
#include <hip/hip_runtime.h>

#define BINS 256
#define EMBV 64          // EMB/4 float4s per row
#define BH   8           // 2*4 flattened batch

typedef float f32x4 __attribute__((ext_vector_type(4)));

// out[bh][i][j][d] = (s_i+s_j)*0.5 + s_i*s_j + T[|i-j|][d]  -- symmetric in (i,j).
// Compute lower triangle (j <= i), store to [i][j] and mirror [j][i].
// Triangle fold for balance: block b handles rows i=b and i=255-b (~257 j-steps).
// 512 threads: d4 = t&63 (float4 lane), tj = t>>6 (j sub-slot 0..7).
// Wave = one (j) value x full d-row -> every load/store is a contiguous 1 KiB line.
// Non-temporal stores keep the 537 MB output stream from evicting the
// 2.25 MB L2-resident inputs.
__global__ __launch_bounds__(512) void outputhead_sym(
        const f32x4* __restrict__ seq4,   // [BH][BINS][EMBV]
        const f32x4* __restrict__ tab4,   // [256][EMBV]
        f32x4* __restrict__ out4)         // [BH][BINS][BINS][EMBV]
{
    const int blk = blockIdx.x;
    const int bh  = blk >> 7;          // 0..7
    const int b   = blk & 127;         // 0..127
    const int t   = threadIdx.x;       // 0..511
    const int d4  = t & 63;
    const int tj  = t >> 6;            // 0..7 (uniform per wave)

    const size_t seq_base = (size_t)bh * BINS * EMBV;
    const size_t out_bh   = (size_t)bh * BINS * BINS * EMBV;

    #pragma unroll
    for (int r = 0; r < 2; ++r) {
        const int i = (r == 0) ? b : (BINS - 1 - b);
        const f32x4 si = seq4[seq_base + (size_t)i * EMBV + d4];
        const size_t out_row_i = out_bh + (size_t)i * BINS * EMBV;

        for (int jb = 0; jb <= i; jb += 8) {
            const int j = jb + tj;         // uniform across the wave
            if (j > i) break;              // wave-uniform branch (tail only)

            const f32x4 sj = seq4[seq_base + (size_t)j * EMBV + d4];
            const f32x4 tv = tab4[(size_t)(i - j) * EMBV + d4];

            const f32x4 o = (si + sj) * 0.5f + si * sj + tv;

            __builtin_nontemporal_store(o, &out4[out_row_i + (size_t)j * EMBV + d4]);
            if (j != i) {
                __builtin_nontemporal_store(
                    o, &out4[out_bh + (size_t)j * BINS * EMBV + (size_t)i * EMBV + d4]);
            }
        }
    }
}

extern "C" void kernel_launch(void* const* d_in, const int* in_sizes, int n_in,
                              void* d_out, int out_size, void* d_ws, size_t ws_size,
                              hipStream_t stream) {
    const f32x4* seq4 = (const f32x4*)d_in[0];  // (2,4,256,256) fp32
    const f32x4* tab4 = (const f32x4*)d_in[1];  // (256,256) fp32
    f32x4* out4 = (f32x4*)d_out;                // (2,4,256,256,256) fp32

    dim3 grid(BH * 128);    // 1024 blocks: 8 bh x 128 folded row-pairs
    dim3 block(512);
    outputhead_sym<<<grid, block, 0, stream>>>(seq4, tab4, out4);
}

// Round 4
// 98.212 us; speedup vs baseline: 1.1672x; 1.1672x over previous
//
#include <hip/hip_runtime.h>

#define BINS 256
#define EMBV 64          // EMB/4 float4s per row
#define BH   8           // 2*4 flattened batch

typedef float f32x4 __attribute__((ext_vector_type(4)));

// out[bh][i][j][d] = (s_i+s_j)*0.5 + s_i*s_j + T[|i-j|][d]
//
// One block per (bh,i). XCD-grouped mapping: block->XCD is blockIdx%8 on
// MI355X, so bh = blk&7 pins each bh's whole working set (seq[bh] 256KB +
// table 256KB = 512KB) to one XCD's L2, instead of all 8 bh (2.25MB) on
// every XCD competing with the 537MB write stream.
// 256 threads: d4 = t&63 float4 lane, tj = t>>6 j-subslot; each wave
// loads/stores contiguous 1KiB lines.
__global__ __launch_bounds__(256) void outputhead_kernel(
        const f32x4* __restrict__ seq4,   // [BH][BINS][EMBV]
        const f32x4* __restrict__ tab4,   // [256][EMBV]
        f32x4* __restrict__ out4)         // [BH][BINS][BINS][EMBV]
{
    const int blk = blockIdx.x;
    const int bh  = blk & 7;           // XCD-grouped: one bh per XCD
    const int i   = blk >> 3;          // consecutive same-XCD blocks -> adjacent i
    const int t   = threadIdx.x;
    const int d4  = t & 63;
    const int tj  = t >> 6;            // 0..3

    const f32x4 si = seq4[(bh * BINS + i) * EMBV + d4];

    const size_t seq_bh_base  = (size_t)bh * BINS * EMBV;
    const size_t out_row_base = ((size_t)(bh * BINS + i)) * BINS * EMBV;

    #pragma unroll 4
    for (int jb = 0; jb < BINS; jb += 4) {
        const int j    = jb + tj;
        const int dist = (i > j) ? (i - j) : (j - i);

        const f32x4 sj = seq4[seq_bh_base + (size_t)j * EMBV + d4];
        const f32x4 tv = tab4[(size_t)dist * EMBV + d4];

        const f32x4 o = (si + sj) * 0.5f + si * sj + tv;

        out4[out_row_base + (size_t)j * EMBV + d4] = o;
    }
}

extern "C" void kernel_launch(void* const* d_in, const int* in_sizes, int n_in,
                              void* d_out, int out_size, void* d_ws, size_t ws_size,
                              hipStream_t stream) {
    const f32x4* seq4 = (const f32x4*)d_in[0];  // (2,4,256,256) fp32
    const f32x4* tab4 = (const f32x4*)d_in[1];  // (256,256) fp32
    f32x4* out4 = (f32x4*)d_out;                // (2,4,256,256,256) fp32

    dim3 grid(BH * BINS);   // 2048 blocks
    dim3 block(256);
    outputhead_kernel<<<grid, block, 0, stream>>>(seq4, tab4, out4);
}